// Round 8
// baseline (195.588 us; speedup 1.0000x reference)
//
#include <hip/hip_runtime.h>

#define N_NODES 16384
#define F_IN    128
#define F_HID   256
#define F_OUT   128
#define LN_EPS  1e-5f
#define CAP     128   // ELL slots/row; P(deg>128) ~ 1e-20 for Poisson(32)
#define HSTR    264   // LDS H-row stride in ushorts (256 + 8 pad -> 2-way banks max)

typedef __attribute__((ext_vector_type(8))) short bf16x8;
typedef __attribute__((ext_vector_type(4))) float f32x4;
typedef unsigned short u16;

__device__ __forceinline__ u16 bf16rne(float f) {
    unsigned u = __float_as_uint(f);
    unsigned r = (u + 0x7fffu + ((u >> 16) & 1u)) >> 16;   // round-to-nearest-even
    return (u16)r;
}
__device__ __forceinline__ float bf_lo(unsigned v) { return __uint_as_float(v << 16); }

// ---------------------------------------------------------------------------
// Prelude (one launch): blockIdx ranges do independent prep work.
//  [0,2048)    : x fp32 -> bf16
//  [2048,2176) : W1 [128k x 256n] -> W1t [256n x 128k] bf16
//  [2176,2304) : W2 [256k x 128n] -> W2t [128n x 256k] bf16
//  [2304,2368) : cur[] = 0
//  2368        : detect int64 vs int32 edge_index (odd u32 words all zero)
__global__ void prelude_kernel(const float* __restrict__ x, u16* __restrict__ xb,
                               const float* __restrict__ W1, u16* __restrict__ W1t,
                               const float* __restrict__ W2, u16* __restrict__ W2t,
                               int* __restrict__ cur, const unsigned* __restrict__ ei,
                               int* __restrict__ mode) {
    int b = blockIdx.x, t = threadIdx.x;
    if (b < 2048) {
        int i = (b * 256 + t) * 4;
        float4 v = *(const float4*)&x[i];
        ushort4 o;
        o.x = bf16rne(v.x); o.y = bf16rne(v.y); o.z = bf16rne(v.z); o.w = bf16rne(v.w);
        *(ushort4*)&xb[i] = o;
    } else if (b < 2176) {
        int id = (b - 2048) * 256 + t;        // [0, 32768)
        int n = id >> 7, k = id & 127;
        W1t[id] = bf16rne(W1[(size_t)k * F_HID + n]);
    } else if (b < 2304) {
        int id = (b - 2176) * 256 + t;        // [0, 32768)
        int n = id >> 8, k = id & 255;
        W2t[id] = bf16rne(W2[(size_t)k * F_OUT + n]);
    } else if (b < 2368) {
        cur[(b - 2304) * 256 + t] = 0;
    } else {
        __shared__ int nz;
        if (t == 0) nz = 0;
        __syncthreads();
        for (int it = 0; it < 4; ++it) {
            int idx = 2 * (t + it * 256) + 1;
            if (ei[idx] != 0u) nz = 1;        // benign race
        }
        __syncthreads();
        if (t == 0) *mode = (nz == 0) ? 1 : 0;  // 1 => int64
    }
}

// ---------------------------------------------------------------------------
// ELL fill: 4 independent edges/thread -> 4 overlapping atomic chains.
// Entry = int2{col, edge_id}.
__global__ void fill_kernel(const void* __restrict__ ei, const int* __restrict__ mode,
                            int* __restrict__ cur, int2* __restrict__ ed, int E) {
    int base = blockIdx.x * 1024 + threadIdx.x;
    int m = *mode;
#pragma unroll
    for (int u = 0; u < 4; ++u) {
        int e = base + u * 256;
        if (e >= E) continue;
        int r, c;
        if (m) {
            const long long* p = (const long long*)ei;
            r = (int)p[e]; c = (int)p[e + E];
        } else {
            const int* p = (const int*)ei;
            r = p[e]; c = p[e + E];
        }
        if (((unsigned)r | (unsigned)c) >= N_NODES) continue;   // replay-safety guard
        int pos = atomicAdd(&cur[r], 1);
        if (pos < CAP) ed[r * CAP + pos] = make_int2(c, e);
    }
}

// ---------------------------------------------------------------------------
// Per-row dedupe (last edge_id wins) + degree. One wave per row. Emits packed
// descriptors edp[i] = (bf16(w) << 16) | col, padded to a multiple of 16 with
// {col=r, w=0}. invdeg fp32 exact. cur[r] := padded length.
__global__ void dedupe_kernel(const float* __restrict__ ew, int* __restrict__ cur,
                              const int2* __restrict__ ed, unsigned* __restrict__ edp,
                              float* __restrict__ invdeg) {
    __shared__ int scol[4][CAP];
    __shared__ int seid[4][CAP];
    int wave = threadIdx.x >> 6, lane = threadIdx.x & 63;
    int r = blockIdx.x * 4 + wave;
    int d = cur[r];
    if (d > CAP) d = CAP;
    int dpad = (d + 15) & ~15;
    if (dpad > CAP) dpad = CAP;
    const int2* row = ed + r * CAP;
    for (int i = lane; i < d; i += 64) {
        int2 e = row[i];
        scol[wave][i] = e.x;
        seid[wave][i] = e.y;
    }
    __syncthreads();
    float wsum = 0.0f;
    unsigned* orow = edp + r * CAP;
    for (int i = lane; i < dpad; i += 64) {
        if (i < d) {
            int myc = scol[wave][i], mye = seid[wave][i];
            bool kill = false;
            for (int j = 0; j < d; ++j)
                if (scol[wave][j] == myc && seid[wave][j] > mye) { kill = true; break; }
            float w = kill ? 0.0f : ew[mye];
            wsum += w;
            orow[i] = ((unsigned)bf16rne(w) << 16) | (unsigned)myc;
        } else {
            orow[i] = (unsigned)r;            // col=r, w=+0.0 pad
        }
    }
    for (int off = 32; off; off >>= 1) wsum += __shfl_xor(wsum, off, 64);
    if (lane == 0) {
        invdeg[r] = 1.0f / (1.0f + wsum);     // +1 self-loop; >=1 so clip no-op
        cur[r] = dpad;
    }
}

// ---------------------------------------------------------------------------
// Split gather SpMM: one wave = (row, 64-col feature half). half = blockIdx&1
// so round-robin block->XCD mapping pins each 2 MB xb-half to one XCD set.
// Descriptors are wave-uniform (scalar-pipe loads); per-edge vector work is
// 3 instructions: global_load_ushort (saddr+lane), shift, fma.
__launch_bounds__(256)
__global__ void spmm_kernel(const u16* __restrict__ xb, const int* __restrict__ cur,
                            const unsigned* __restrict__ edp, const float* __restrict__ invdeg,
                            const float* __restrict__ bias, void* __restrict__ outp,
                            int out_bf16) {
    int wid = threadIdx.x >> 6, lane = threadIdx.x & 63;
    int half = blockIdx.x & 1;
    int r = __builtin_amdgcn_readfirstlane((blockIdx.x >> 1) * 4 + wid);
    int hb = half * 64;
    int sidx = r * F_IN + hb + lane;
    float acc = bf_lo((unsigned)xb[sidx]);     // self-loop, weight 1
    int dpad = cur[r];
    const unsigned* rowp = edp + r * CAP;
    for (int j = 0; j < dpad; j += 16) {
        unsigned dsc[16];
#pragma unroll
        for (int u = 0; u < 16; ++u) dsc[u] = rowp[j + u];   // scalar-pipe loads
#pragma unroll
        for (int u = 0; u < 16; ++u) {
            int col = (int)(dsc[u] & 0xffffu);               // scalar math
            float w = __uint_as_float(dsc[u] & 0xffff0000u); // bf16 weight
            unsigned v = (unsigned)xb[col * F_IN + hb + lane];
            acc += w * bf_lo(v);
        }
    }
    float o = acc * invdeg[r];
    if (bias) o += bias[hb + lane];
    if (out_bf16) ((u16*)outp)[sidx] = bf16rne(o);
    else          ((float*)outp)[sidx] = o;
}

// ---------------------------------------------------------------------------
// MFMA MLP: h2 = relu(LN(h0 @ W1 + b1)) @ W2  in bf16 (b2 added in spmm2).
// One wave owns 16 rows end-to-end; 4 waves/block (64 rows), grid 256.
// mfma_f32_16x16x32_bf16: C/D col=lane&15 row=quad*4+reg; A[m=lane&15][k=quad*8+j].
// W1t/W2t are [n][k] bf16 so B-frags are contiguous 16B loads (L1/L2-resident).
__launch_bounds__(256)
__global__ void mlp_mfma_kernel(const u16* __restrict__ h0b,
                                const u16* __restrict__ W1t,
                                const u16* __restrict__ W2t,
                                const float* __restrict__ b1,
                                const float* __restrict__ ln_g, const float* __restrict__ ln_b,
                                u16* __restrict__ h2b) {
    __shared__ u16 Hs[4][16 * HSTR];    // ~33 KB
    int t = threadIdx.x;
    int wid = t >> 6, lane = t & 63;
    int lnid = lane & 15, quad = lane >> 4;
    int R = blockIdx.x * 64 + wid * 16;
    u16* H = Hs[wid];

    // ---- stage A: C1[16x256] = h0[R.., 128] @ W1, K=128 ----
    bf16x8 a[4];
#pragma unroll
    for (int ch = 0; ch < 4; ++ch)
        a[ch] = *(const bf16x8*)&h0b[(size_t)(R + lnid) * F_IN + ch * 32 + quad * 8];
    f32x4 acc[16];
#pragma unroll
    for (int ct = 0; ct < 16; ++ct) {
        f32x4 c = {0.0f, 0.0f, 0.0f, 0.0f};
        const u16* wrow = &W1t[(size_t)(ct * 16 + lnid) * F_IN];
#pragma unroll
        for (int ch = 0; ch < 4; ++ch) {
            bf16x8 b = *(const bf16x8*)&wrow[ch * 32 + quad * 8];
            c = __builtin_amdgcn_mfma_f32_16x16x32_bf16(a[ch], b, c, 0, 0, 0);
        }
        acc[ct] = c;
    }
    // bias + LN stats (rows live in (quad,reg); cols in (ct,lnid))
    float s[4] = {0, 0, 0, 0}, q[4] = {0, 0, 0, 0};
#pragma unroll
    for (int ct = 0; ct < 16; ++ct) {
        float bv = b1[ct * 16 + lnid];
#pragma unroll
        for (int r = 0; r < 4; ++r) {
            float v = acc[ct][r] + bv;
            acc[ct][r] = v;
            s[r] += v; q[r] += v * v;
        }
    }
#pragma unroll
    for (int r = 0; r < 4; ++r)
        for (int off = 1; off < 16; off <<= 1) {
            s[r] += __shfl_xor(s[r], off, 64);
            q[r] += __shfl_xor(q[r], off, 64);
        }
    float mean[4], rinv[4];
#pragma unroll
    for (int r = 0; r < 4; ++r) {
        mean[r] = s[r] * (1.0f / F_HID);
        float var = q[r] * (1.0f / F_HID) - mean[r] * mean[r];
        rinv[r] = rsqrtf(var + LN_EPS);
    }
#pragma unroll
    for (int ct = 0; ct < 16; ++ct) {
        int c = ct * 16 + lnid;
        float g = ln_g[c], bb = ln_b[c];
#pragma unroll
        for (int r = 0; r < 4; ++r) {
            float v = fmaxf((acc[ct][r] - mean[r]) * rinv[r] * g + bb, 0.0f);
            H[(quad * 4 + r) * HSTR + c] = bf16rne(v);
        }
    }
    __syncthreads();   // drain LDS writes before A-layout reads

    // ---- stage B: C2[16x128] = H[16x256] @ W2, K=256 ----
    bf16x8 a2[8];
#pragma unroll
    for (int ch = 0; ch < 8; ++ch)
        a2[ch] = *(const bf16x8*)&H[lnid * HSTR + ch * 32 + quad * 8];
#pragma unroll
    for (int ct = 0; ct < 8; ++ct) {
        f32x4 c = {0.0f, 0.0f, 0.0f, 0.0f};
        const u16* wrow = &W2t[(size_t)(ct * 16 + lnid) * F_HID];
#pragma unroll
        for (int ch = 0; ch < 8; ++ch) {
            bf16x8 b = *(const bf16x8*)&wrow[ch * 32 + quad * 8];
            c = __builtin_amdgcn_mfma_f32_16x16x32_bf16(a2[ch], b, c, 0, 0, 0);
        }
        // C2 -> LDS repack area (stride 132 ushorts)
#pragma unroll
        for (int r = 0; r < 4; ++r)
            H[(quad * 4 + r) * 132 + ct * 16 + lnid] = bf16rne(c[r]);
    }
    __syncthreads();   // drain before coalesced readback

    // coalesced store: 16 rows x 128 bf16
#pragma unroll
    for (int p = 0; p < 8; ++p) {
        int flat = p * 64 + lane;           // ushort4 id in [0,512)
        int m = flat >> 5, cg = flat & 31;
        *(ushort4*)&h2b[(size_t)(R + m) * F_OUT + cg * 4] =
            *(const ushort4*)&H[m * 132 + cg * 4];
    }
}

// ---------------------------------------------------------------------------
extern "C" void kernel_launch(void* const* d_in, const int* in_sizes, int n_in,
                              void* d_out, int out_size, void* d_ws, size_t ws_size,
                              hipStream_t stream) {
    const float* x   = (const float*)d_in[0];
    const void*  ei  = d_in[1];
    const float* ew  = (const float*)d_in[2];
    const float* W1  = (const float*)d_in[3];
    const float* b1  = (const float*)d_in[4];
    const float* W2  = (const float*)d_in[5];
    const float* b2  = (const float*)d_in[6];
    const float* lng = (const float*)d_in[7];
    const float* lnb = (const float*)d_in[8];
    float* out = (float*)d_out;
    int E = in_sizes[2];

    char* w = (char*)d_ws;
    size_t off = 0;
    auto take = [&](size_t bytes) -> char* {
        char* p = w + off;
        off += (bytes + 255) & ~(size_t)255;
        return p;
    };
    int*      cur    = (int*)take((size_t)N_NODES * 4);
    float*    invdeg = (float*)take((size_t)N_NODES * 4);
    int2*     ed     = (int2*)take((size_t)N_NODES * CAP * 8);
    unsigned* edp    = (unsigned*)take((size_t)N_NODES * CAP * 4);
    u16* xb  = (u16*)take((size_t)N_NODES * F_IN * 2);
    u16* h0b = (u16*)take((size_t)N_NODES * F_IN * 2);
    u16* h2b = (u16*)take((size_t)N_NODES * F_OUT * 2);
    u16* W1t = (u16*)take((size_t)F_IN * F_HID * 2);
    u16* W2t = (u16*)take((size_t)F_HID * F_OUT * 2);
    int* mode = (int*)take(4);

    prelude_kernel<<<2369, 256, 0, stream>>>(x, xb, W1, W1t, W2, W2t, cur,
                                             (const unsigned*)ei, mode);
    fill_kernel<<<(E + 1023) / 1024, 256, 0, stream>>>(ei, mode, cur, ed, E);
    dedupe_kernel<<<N_NODES / 4, 256, 0, stream>>>(ew, cur, ed, edp, invdeg);
    // h0b = bf16( D^-1 (A+I) x )
    spmm_kernel<<<N_NODES / 2, 256, 0, stream>>>(xb, cur, edp, invdeg, nullptr, h0b, 1);
    // h2b = bf16( relu(LN(h0 W1 + b1)) W2 )
    mlp_mfma_kernel<<<N_NODES / 64, 256, 0, stream>>>(h0b, W1t, W2t, b1, lng, lnb, h2b);
    // out = D^-1 (A+I) h2 + b2   (== (D^-1 (A+I) h) W2 + b2 by linearity)
    spmm_kernel<<<N_NODES / 2, 256, 0, stream>>>(h2b, cur, edp, invdeg, b2, out, 0);
}